// Round 4
// baseline (646.401 us; speedup 1.0000x reference)
//
#include <hip/hip_runtime.h>
#include <hip/hip_bf16.h>
#include <math.h>

typedef __bf16 bf16_t;
typedef __bf16 bf16x8 __attribute__((ext_vector_type(8)));
typedef __bf16 bf16x4 __attribute__((ext_vector_type(4)));
typedef float  floatx4 __attribute__((ext_vector_type(4)));

#define NB 512      // batch
#define DI 256      // feature dim

__device__ __forceinline__ float lrelu_f(float x){ return x >= 0.f ? x : 0.2f*x; }
__device__ __forceinline__ float elu_f(float x){ return x > 0.f ? x : expm1f(x); }

// ---------------- dtype probe: fp32 (flag=1) vs bf16 (flag=0) -----------------
__global__ __launch_bounds__(256)
void detect_k(const void* __restrict__ probe, int* __restrict__ flag)
{
    __shared__ int cnt_s;
    if (threadIdx.x == 0) cnt_s = 0;
    __syncthreads();
    const unsigned short* u = (const unsigned short*)probe;
    int c = 0;
    for (int i = threadIdx.x; i < 16384; i += 256) {
        int e = (u[i] >> 7) & 0xFF;
        if (e >= 0x90) c++;
    }
    atomicAdd(&cnt_s, c);
    __syncthreads();
    if (threadIdx.x == 0) *flag = (cnt_s > 64) ? 1 : 0;
}

// ---------------- small buffers (biases, attn vecs) -> bf16 ws copies ---------
struct SCEnt { const void* s; bf16_t* d; int n; };
struct SCArgs { SCEnt e[16]; int cnt; };

__global__ __launch_bounds__(256)
void smallconv_k(SCArgs a, const int* __restrict__ flag)
{
    int isf = *flag;
    for (int k = 0; k < a.cnt; ++k) {
        int n = a.e[k].n;
        for (int i = threadIdx.x + blockIdx.x * 256; i < n; i += gridDim.x * 256) {
            float v = isf ? ((const float*)a.e[k].s)[i]
                          : (float)((const bf16_t*)a.e[k].s)[i];
            a.e[k].d[i] = (bf16_t)v;
        }
    }
}

// ---------------- fused dtype-aware transposes: WT[n][k] = W[eoff + k*256 + n]
struct TDesc { const void* W; size_t eoff; bf16_t* WT; int K; int tstart; };
struct TArgs { TDesc d[15]; int nd; };

__global__ __launch_bounds__(256)
void transpose_multi_k(TArgs ta, const int* __restrict__ flagp)
{
    __shared__ bf16_t tile[32][33];
    const int isf = *flagp;
    const int bx = blockIdx.x;
    int di = 0;
    while (di + 1 < ta.nd && bx >= ta.d[di + 1].tstart) ++di;
    const void* Wbase = ta.d[di].W;
    const size_t eoff = ta.d[di].eoff;
    bf16_t* WT        = ta.d[di].WT;
    const int K       = ta.d[di].K;
    const int ti      = bx - ta.d[di].tstart;
    const int tk      = K >> 5;            // tiles along K
    const int kb      = (ti % tk) * 32;
    const int nb      = (ti / tk) * 32;    // N = 256 fixed
    const int tx = threadIdx.x & 31, ty = threadIdx.x >> 5;
    #pragma unroll
    for (int rr = 0; rr < 4; ++rr) {
        int r = ty + rr * 8;
        size_t idx = eoff + (size_t)(kb + r) * 256 + nb + tx;
        tile[r][tx] = isf ? (bf16_t)((const float*)Wbase)[idx]
                          : ((const bf16_t*)Wbase)[idx];
    }
    __syncthreads();
    #pragma unroll
    for (int rr = 0; rr < 4; ++rr) {
        int r = ty + rr * 8;
        WT[(size_t)(nb + r) * K + kb + tx] = tile[tx][r];
    }
}

// ---------------- descriptor-fused bf16 MFMA GEMM -----------------------------
// 64x64 tiles; 1-D grid with N-FASTEST ordering: bx = mb*4 + nb. The four
// n-siblings of one A-panel dispatch back-to-back, so the panel is fetched
// from HBM once and the other three reads hit L2/L3 (round-2 re-fetch fix
// without round-3's occupancy collapse).
#define BM 64
#define BN 64
#define BK 32
#define LST 40   // LDS row stride (elems); 80B rows keep b128 16B-aligned

struct GDesc {
    const void* A; const bf16_t* WT; const bf16_t* bias; bf16_t* out;
    int Kin, in_stride_b, in_off, rows_pb, a_is_ext, out_stride_b, out_off, mb_start;
};
struct GArgs { GDesc d[9]; int nd; };

__global__ __launch_bounds__(256)
void gemm_multi_k(GArgs ga, const int* __restrict__ flagp)
{
    __shared__ bf16_t As[BM * LST];
    __shared__ bf16_t Bs[BN * LST];

    const int mb = blockIdx.x >> 2;          // m-block (descriptor space)
    const int n0 = (blockIdx.x & 3) * BN;    // n-offset, fastest-varying
    int di = 0;
    while (di + 1 < ga.nd && mb >= ga.d[di + 1].mb_start) ++di;

    const void*   A        = ga.d[di].A;
    const bf16_t* WT       = ga.d[di].WT;
    const bf16_t* bias     = ga.d[di].bias;
    bf16_t*       out      = ga.d[di].out;
    const int Kin          = ga.d[di].Kin;
    const int in_stride_b  = ga.d[di].in_stride_b;
    const int in_off       = ga.d[di].in_off;
    const int rows_pb      = ga.d[di].rows_pb;
    const int out_stride_b = ga.d[di].out_stride_b;
    const int out_off      = ga.d[di].out_off;
    const int a_fp32 = ga.d[di].a_is_ext ? *flagp : 0;

    const int t  = threadIdx.x;
    const int m0 = (mb - ga.d[di].mb_start) * BM;

    const int s_row = t >> 2;          // 0..63
    const int s_col = (t & 3) * 8;     // 0,8,16,24

    const int g_row = m0 + s_row;
    const int b_idx = g_row / rows_pb;
    const int i_idx = g_row - b_idx * rows_pb;
    const size_t a_base = (size_t)(b_idx * in_stride_b + in_off + i_idx) * Kin + s_col;
    const bf16_t* w_ptr = WT + (size_t)(n0 + s_row) * Kin + s_col;

    const int wave = t >> 6;
    const int lane = t & 63;
    const int wr = (wave >> 1) * 32;
    const int wc = (wave & 1) * 32;
    const int lm = lane & 15;
    const int lk = (lane >> 4) * 8;

    floatx4 acc[2][2] = {};

    for (int kk = 0; kk < Kin; kk += BK) {
        bf16x8 av;
        if (a_fp32) {
            const float* ap = (const float*)A + a_base + kk;
            float4 f0 = *(const float4*)ap;
            float4 f1 = *(const float4*)(ap + 4);
            av[0] = (bf16_t)f0.x; av[1] = (bf16_t)f0.y;
            av[2] = (bf16_t)f0.z; av[3] = (bf16_t)f0.w;
            av[4] = (bf16_t)f1.x; av[5] = (bf16_t)f1.y;
            av[6] = (bf16_t)f1.z; av[7] = (bf16_t)f1.w;
        } else {
            av = *(const bf16x8*)((const bf16_t*)A + a_base + kk);
        }
        bf16x8 wv = *(const bf16x8*)(w_ptr + kk);
        *(bf16x8*)(&As[s_row * LST + s_col]) = av;
        *(bf16x8*)(&Bs[s_row * LST + s_col]) = wv;
        __syncthreads();

        bf16x8 af0 = *(const bf16x8*)(&As[(wr      + lm) * LST + lk]);
        bf16x8 af1 = *(const bf16x8*)(&As[(wr + 16 + lm) * LST + lk]);
        bf16x8 bf0 = *(const bf16x8*)(&Bs[(wc      + lm) * LST + lk]);
        bf16x8 bf1 = *(const bf16x8*)(&Bs[(wc + 16 + lm) * LST + lk]);

        acc[0][0] = __builtin_amdgcn_mfma_f32_16x16x32_bf16(af0, bf0, acc[0][0], 0, 0, 0);
        acc[0][1] = __builtin_amdgcn_mfma_f32_16x16x32_bf16(af0, bf1, acc[0][1], 0, 0, 0);
        acc[1][0] = __builtin_amdgcn_mfma_f32_16x16x32_bf16(af1, bf0, acc[1][0], 0, 0, 0);
        acc[1][1] = __builtin_amdgcn_mfma_f32_16x16x32_bf16(af1, bf1, acc[1][1], 0, 0, 0);
        __syncthreads();
    }

    const int q = lane >> 4;
    #pragma unroll
    for (int i = 0; i < 2; ++i)
      #pragma unroll
      for (int j = 0; j < 2; ++j)
        #pragma unroll
        for (int r = 0; r < 4; ++r) {
            int row = m0 + wr + i * 16 + q * 4 + r;
            int col = n0 + wc + j * 16 + lm;
            int bb = row / rows_pb;
            int ii = row - bb * rows_pb;
            float v = acc[i][j][r];
            if (bias) v += (float)bias[col];
            out[(size_t)(bb * out_stride_b + out_off + ii) * DI + col] = (bf16_t)v;
        }
}

// ---------------- fused attention scores --------------------------------------
struct SDesc { const bf16_t* Wh; const bf16_t* as_; const bf16_t* ad_;
               float* s; float* d; int bstart; };
struct SArgs { SDesc e[3]; int nd; };

__global__ __launch_bounds__(256)
void scores_multi_k(SArgs sa)
{
    const int bx = blockIdx.x;
    int di = 0;
    while (di + 1 < sa.nd && bx >= sa.e[di + 1].bstart) ++di;
    const bf16_t* Wh    = sa.e[di].Wh;
    const bf16_t* a_src = sa.e[di].as_;
    const bf16_t* a_dst = sa.e[di].ad_;
    float* src = sa.e[di].s;
    float* dst = sa.e[di].d;

    int wid  = (bx - sa.e[di].bstart) * 4 + (threadIdx.x >> 6);
    int lane = threadIdx.x & 63;
    bf16x4 wv = *(const bf16x4*)(Wh + (size_t)wid * DI + lane * 4);
    bf16x4 sv = *(const bf16x4*)(a_src + lane * 4);
    bf16x4 dv = *(const bf16x4*)(a_dst + lane * 4);
    float s = 0.f, d = 0.f;
    #pragma unroll
    for (int i = 0; i < 4; ++i) {
        float w = (float)wv[i];
        s += w * (float)sv[i];
        d += w * (float)dv[i];
    }
    #pragma unroll
    for (int off = 32; off > 0; off >>= 1) {
        s += __shfl_down(s, off);
        d += __shfl_down(d, off);
    }
    if (lane == 0) { src[wid] = s; dst[wid] = d; }
}

// ---------------- hub aggregation helpers -------------------------------------
__device__ __forceinline__ float hub20(const bf16_t* __restrict__ Wh,
                                       const float* __restrict__ s,
                                       const float* __restrict__ d,
                                       int b, int c, int e)
{
    int base = b * 63 + 3 + c * 20;
    float ss = s[b * 63 + c];
    float ev[20], mx = -1e30f;
    #pragma unroll
    for (int i = 0; i < 20; ++i) { ev[i] = lrelu_f(ss + d[base + i]); mx = fmaxf(mx, ev[i]); }
    float sw = 0.f, acc = 0.f;
    #pragma unroll
    for (int i = 0; i < 20; ++i) {
        float w = expf(ev[i] - mx);
        sw  += w;
        acc += w * (float)Wh[(size_t)(base + i) * DI + e];
    }
    return acc / sw;
}

__device__ __forceinline__ float hub_tri(const bf16_t* __restrict__ Wh1,
                                         const float* __restrict__ s1,
                                         const float* __restrict__ d1,
                                         int b, int c, int e)
{
    int m0 = (c == 0) ? 1 : 0, m1 = (c == 2) ? 1 : 2;
    float ss = s1[b * 3 + c];
    float e0 = lrelu_f(ss + d1[b * 3 + m0]);
    float e1 = lrelu_f(ss + d1[b * 3 + m1]);
    float mx = fmaxf(e0, e1);
    float w0 = expf(e0 - mx), w1 = expf(e1 - mx);
    return (w0 * (float)Wh1[(size_t)(b * 3 + m0) * DI + e] +
            w1 * (float)Wh1[(size_t)(b * 3 + m1) * DI + e]) / (w0 + w1);
}

// ---------------- stage aggregations ------------------------------------------
__global__ __launch_bounds__(256)
void agg1_k(const bf16_t* __restrict__ Wh1, const float* __restrict__ s1,
            const float* __restrict__ d1, bf16_t* __restrict__ nodes2)
{
    int blk = blockIdx.x;
    int b = blk / 3, n = blk - b * 3;
    int e = threadIdx.x;
    float v = hub_tri(Wh1, s1, d1, b, n, e);
    nodes2[(size_t)(b * 63 + n) * DI + e] = (bf16_t)elu_f(v);
}

__global__ __launch_bounds__(256)
void agg2_k(const bf16_t* __restrict__ Wh1, const bf16_t* __restrict__ Wh2,
            const float* __restrict__ s1, const float* __restrict__ d1,
            const float* __restrict__ s2, const float* __restrict__ d2,
            bf16_t* __restrict__ nodes3)
{
    int blk = blockIdx.x;
    int b = blk / 63, n = blk - b * 63;
    int e = threadIdx.x;
    float v;
    if (n >= 3) {
        int c = (n - 3) / 20;
        v = (float)Wh2[(size_t)(b * 63 + c) * DI + e];
    } else {
        v = hub_tri(Wh1, s1, d1, b, n, e) + hub20(Wh2, s2, d2, b, n, e);
    }
    nodes3[(size_t)(b * 123 + n) * DI + e] = (bf16_t)elu_f(v);
}

__global__ __launch_bounds__(256)
void agg3_k(const bf16_t* __restrict__ Wh1, const bf16_t* __restrict__ Wh2,
            const bf16_t* __restrict__ Wh3,
            const float* __restrict__ s1, const float* __restrict__ d1,
            const float* __restrict__ s2, const float* __restrict__ d2,
            const float* __restrict__ s3, const float* __restrict__ d3,
            void* __restrict__ out, const int* __restrict__ flagp)
{
    int isf = *flagp;
    int blk = blockIdx.x;
    int b = blk / 123, n = blk - b * 123;
    int e = threadIdx.x;
    float v;
    if (n >= 63) {
        int c = (n - 63) / 20;
        v = (float)Wh3[(size_t)(b * 63 + c) * DI + e];
    } else if (n >= 3) {
        int c = (n - 3) / 20;
        v = (float)Wh2[(size_t)(b * 63 + c) * DI + e];
    } else {
        v = hub_tri(Wh1, s1, d1, b, n, e)
          + hub20(Wh2, s2, d2, b, n, e)
          + hub20(Wh3, s3, d3, b, n, e);
    }
    float r = elu_f(v);
    size_t oi = (size_t)(b * 123 + n) * DI + e;
    if (isf) ((float*)out)[oi] = r;
    else     ((bf16_t*)out)[oi] = (bf16_t)r;
}

// ------------------------------------------------------------------------------
extern "C" void kernel_launch(void* const* d_in, const int* in_sizes, int n_in,
                              void* d_out, int out_size, void* d_ws, size_t ws_size,
                              hipStream_t stream)
{
    (void)in_sizes; (void)n_in; (void)out_size; (void)ws_size;
    const void *scene_tv=d_in[0], *face_tv=d_in[1], *text_tv=d_in[2],
               *scene_refs=d_in[3], *face_refs=d_in[4], *text_refs=d_in[5],
               *scene_ra=d_in[6], *face_ra=d_in[7], *text_ra=d_in[8],
               *Ws1=d_in[9],  *bs1=d_in[10], *Wf1=d_in[11], *bf1=d_in[12],
               *Wt1=d_in[13], *bt1=d_in[14],
               *G1W=d_in[15], *G1as=d_in[16], *G1ad=d_in[17],
               *Ws2=d_in[18], *bs2=d_in[19], *Wf2=d_in[20], *bf2=d_in[21],
               *Wt2=d_in[22], *bt2=d_in[23],
               *G2W=d_in[24], *G2as=d_in[25], *G2ad=d_in[26],
               *Ws3=d_in[27], *bs3=d_in[28], *Wf3=d_in[29], *bf3=d_in[30],
               *Wt3=d_in[31], *bt3=d_in[32],
               *G3W=d_in[33], *G3as=d_in[34], *G3ad=d_in[35];

    char* p = (char*)d_ws;
    auto carveB = [&](size_t elems) -> bf16_t* { bf16_t* r = (bf16_t*)p; p += ((elems*2 + 255) & ~(size_t)255); return r; };
    auto carveF = [&](size_t elems) -> float*  { float*  r = (float*)p;  p += ((elems*4 + 255) & ~(size_t)255); return r; };
    auto carveI = [&]() -> int* { int* r = (int*)p; p += 256; return r; };

    int* flag = carveI();

    bf16_t* Ws1T = carveB(1024*256); bf16_t* Wf1T = carveB(1024*256); bf16_t* Wt1T = carveB(2048*256);
    bf16_t* Ws2T = carveB(1024*256); bf16_t* Wf2T = carveB(1024*256); bf16_t* Wt2T = carveB(2048*256);
    bf16_t* Ws3T = carveB(1024*256); bf16_t* Wf3T = carveB(1024*256); bf16_t* Wt3T = carveB(1024*256);
    bf16_t* G1WT = carveB(256*256);
    bf16_t* G2WT = carveB(2*256*256);
    bf16_t* G3WT = carveB(3*256*256);

    bf16_t* cb[9];
    for (int i = 0; i < 9; ++i) cb[i] = carveB(256);
    bf16_t* a1s = carveB(256); bf16_t* a1d = carveB(256);
    bf16_t* a2s = carveB(512); bf16_t* a2d = carveB(512);
    bf16_t* a3s = carveB(768); bf16_t* a3d = carveB(768);

    bf16_t* nodes1 = carveB((size_t)NB*3*DI);
    bf16_t* nodes2 = carveB((size_t)NB*63*DI);
    bf16_t* nodes3 = carveB((size_t)NB*123*DI);
    bf16_t* Wh1    = carveB((size_t)NB*3*DI);
    bf16_t* Wh2    = carveB((size_t)NB*63*DI);
    bf16_t* Wh3    = carveB((size_t)NB*63*DI);
    float* s1s = carveF(NB*3);  float* s1d = carveF(NB*3);
    float* s2s = carveF(NB*63); float* s2d = carveF(NB*63);
    float* s3s = carveF(NB*63); float* s3d = carveF(NB*63);

    detect_k<<<1, 256, 0, stream>>>(Ws1, flag);

    SCArgs sca;
    const void* ssrc[15] = { bs1, bf1, bt1, bs2, bf2, bt2, bs3, bf3, bt3,
                             G1as, G1ad, G2as, G2ad, G3as, G3ad };
    bf16_t* sdst[15] = { cb[0],cb[1],cb[2],cb[3],cb[4],cb[5],cb[6],cb[7],cb[8],
                         a1s, a1d, a2s, a2d, a3s, a3d };
    int sn[15] = { 256,256,256,256,256,256,256,256,256, 256,256,512,512,768,768 };
    for (int i = 0; i < 15; ++i) { sca.e[i].s = ssrc[i]; sca.e[i].d = sdst[i]; sca.e[i].n = sn[i]; }
    sca.cnt = 15;
    smallconv_k<<<1, 256, 0, stream>>>(sca, flag);

    // ---- all 15 weight transposes in one launch ----
    TArgs ta; ta.nd = 0; int tcum = 0;
    auto addT = [&](const void* W, size_t eoff, bf16_t* WT, int K) {
        ta.d[ta.nd].W = W; ta.d[ta.nd].eoff = eoff; ta.d[ta.nd].WT = WT;
        ta.d[ta.nd].K = K; ta.d[ta.nd].tstart = tcum;
        tcum += (K / 32) * 8; ta.nd++;
    };
    addT(Ws1, 0, Ws1T, 1024); addT(Wf1, 0, Wf1T, 1024); addT(Wt1, 0, Wt1T, 2048);
    addT(Ws2, 0, Ws2T, 1024); addT(Wf2, 0, Wf2T, 1024); addT(Wt2, 0, Wt2T, 2048);
    addT(Ws3, 0, Ws3T, 1024); addT(Wf3, 0, Wf3T, 1024); addT(Wt3, 0, Wt3T, 1024);
    addT(G1W, 0,      G1WT,          256);
    addT(G2W, 0,      G2WT,          256); addT(G2W, 65536,  G2WT + 65536,  256);
    addT(G3W, 0,      G3WT,          256); addT(G3W, 65536,  G3WT + 65536,  256);
    addT(G3W, 131072, G3WT + 131072, 256);
    transpose_multi_k<<<tcum, 256, 0, stream>>>(ta, flag);

    auto addG = [](GArgs& A, int& cum, const void* Ain, int Kin, int isb, int ioff,
                   int rpb, int ext, const bf16_t* WT, const bf16_t* bias,
                   bf16_t* out, int osb, int ooff, int M) {
        GDesc& g = A.d[A.nd];
        g.A = Ain; g.WT = WT; g.bias = bias; g.out = out;
        g.Kin = Kin; g.in_stride_b = isb; g.in_off = ioff; g.rows_pb = rpb;
        g.a_is_ext = ext; g.out_stride_b = osb; g.out_off = ooff; g.mb_start = cum;
        cum += M / 64; A.nd++;
    };

    // ---- ALL nine input projections (no inter-dependencies) in ONE launch ----
    GArgs pg; pg.nd = 0; int pc = 0;
    addG(pg, pc, scene_tv,   1024,  1, 0,  1, 1, Ws1T, cb[0], nodes1,   3,   0, NB);
    addG(pg, pc, face_tv,    1024,  1, 0,  1, 1, Wf1T, cb[1], nodes1,   3,   1, NB);
    addG(pg, pc, text_tv,    2048,  1, 0,  1, 1, Wt1T, cb[2], nodes1,   3,   2, NB);
    addG(pg, pc, scene_refs, 1024, 20, 0, 20, 1, Ws2T, cb[3], nodes2,  63,   3, NB*20);
    addG(pg, pc, face_refs,  1024, 20, 0, 20, 1, Wf2T, cb[4], nodes2,  63,  23, NB*20);
    addG(pg, pc, text_refs,  2048, 20, 0, 20, 1, Wt2T, cb[5], nodes2,  63,  43, NB*20);
    addG(pg, pc, scene_ra,   1024, 20, 0, 20, 1, Ws3T, cb[6], nodes3, 123,  63, NB*20);
    addG(pg, pc, face_ra,    1024, 20, 0, 20, 1, Wf3T, cb[7], nodes3, 123,  83, NB*20);
    addG(pg, pc, text_ra,    1024, 20, 0, 20, 1, Wt3T, cb[8], nodes3, 123, 103, NB*20);
    gemm_multi_k<<<pc * 4, 256, 0, stream>>>(pg, flag);

    // -------- stage 1 --------
    GArgs g1; g1.nd = 0; int c1 = 0;
    addG(g1, c1, nodes1, 256, 3, 0, 3, 0, G1WT, nullptr, Wh1, 3, 0, NB*3);
    gemm_multi_k<<<c1 * 4, 256, 0, stream>>>(g1, flag);

    SArgs s1a; s1a.nd = 1;
    s1a.e[0].Wh = Wh1; s1a.e[0].as_ = a1s; s1a.e[0].ad_ = a1d;
    s1a.e[0].s = s1s; s1a.e[0].d = s1d; s1a.e[0].bstart = 0;
    scores_multi_k<<<NB*3/4, 256, 0, stream>>>(s1a);
    agg1_k<<<NB*3, 256, 0, stream>>>(Wh1, s1s, s1d, nodes2);

    // -------- stage 2 --------
    GArgs g2; g2.nd = 0; int c2 = 0;
    addG(g2, c2, nodes2, 256, 63, 0,  3, 0, G2WT,         nullptr, Wh1,  3, 0, NB*3);
    addG(g2, c2, nodes2, 256, 63, 0, 63, 0, G2WT + 65536, nullptr, Wh2, 63, 0, NB*63);
    gemm_multi_k<<<c2 * 4, 256, 0, stream>>>(g2, flag);

    SArgs s2a; s2a.nd = 2;
    s2a.e[0].Wh = Wh1; s2a.e[0].as_ = a2s;       s2a.e[0].ad_ = a2d;
    s2a.e[0].s = s1s;  s2a.e[0].d = s1d;         s2a.e[0].bstart = 0;
    s2a.e[1].Wh = Wh2; s2a.e[1].as_ = a2s + 256; s2a.e[1].ad_ = a2d + 256;
    s2a.e[1].s = s2s;  s2a.e[1].d = s2d;         s2a.e[1].bstart = NB*3/4;
    scores_multi_k<<<NB*3/4 + NB*63/4, 256, 0, stream>>>(s2a);
    agg2_k<<<NB*63, 256, 0, stream>>>(Wh1, Wh2, s1s, s1d, s2s, s2d, nodes3);

    // -------- stage 3 --------
    GArgs g3; g3.nd = 0; int c3 = 0;
    addG(g3, c3, nodes3, 256, 123,  0,  3, 0, G3WT,          nullptr, Wh1,  3, 0, NB*3);
    addG(g3, c3, nodes3, 256, 123,  0, 63, 0, G3WT + 65536,  nullptr, Wh2, 63, 0, NB*63);
    addG(g3, c3, nodes3, 256, 123,  0,  3, 0, G3WT + 131072, nullptr, Wh3, 63, 0, NB*3);
    addG(g3, c3, nodes3, 256, 123, 63, 60, 0, G3WT + 131072, nullptr, Wh3, 63, 3, NB*60);
    gemm_multi_k<<<c3 * 4, 256, 0, stream>>>(g3, flag);

    SArgs s3a; s3a.nd = 3;
    s3a.e[0].Wh = Wh1; s3a.e[0].as_ = a3s;       s3a.e[0].ad_ = a3d;
    s3a.e[0].s = s1s;  s3a.e[0].d = s1d;         s3a.e[0].bstart = 0;
    s3a.e[1].Wh = Wh2; s3a.e[1].as_ = a3s + 256; s3a.e[1].ad_ = a3d + 256;
    s3a.e[1].s = s2s;  s3a.e[1].d = s2d;         s3a.e[1].bstart = NB*3/4;
    s3a.e[2].Wh = Wh3; s3a.e[2].as_ = a3s + 512; s3a.e[2].ad_ = a3d + 512;
    s3a.e[2].s = s3s;  s3a.e[2].d = s3d;         s3a.e[2].bstart = NB*3/4 + NB*63/4;
    scores_multi_k<<<NB*3/4 + 2*(NB*63/4), 256, 0, stream>>>(s3a);
    agg3_k<<<NB*123, 256, 0, stream>>>(Wh1, Wh2, Wh3, s1s, s1d, s2s, s2d, s3s, s3d,
                                       d_out, flag);
}

// Round 5
// 603.228 us; speedup vs baseline: 1.0716x; 1.0716x over previous
//
#include <hip/hip_runtime.h>
#include <hip/hip_bf16.h>
#include <math.h>

typedef __bf16 bf16_t;
typedef __bf16 bf16x8 __attribute__((ext_vector_type(8)));
typedef __bf16 bf16x4 __attribute__((ext_vector_type(4)));
typedef float  floatx4 __attribute__((ext_vector_type(4)));

#define NB 512      // batch
#define DI 256      // feature dim

__device__ __forceinline__ float lrelu_f(float x){ return x >= 0.f ? x : 0.2f*x; }
__device__ __forceinline__ float elu_f(float x){ return x > 0.f ? x : expm1f(x); }

// ---------------- dtype probe: fp32 (flag=1) vs bf16 (flag=0) -----------------
__global__ __launch_bounds__(256)
void detect_k(const void* __restrict__ probe, int* __restrict__ flag)
{
    __shared__ int cnt_s;
    if (threadIdx.x == 0) cnt_s = 0;
    __syncthreads();
    const unsigned short* u = (const unsigned short*)probe;
    int c = 0;
    for (int i = threadIdx.x; i < 16384; i += 256) {
        int e = (u[i] >> 7) & 0xFF;
        if (e >= 0x90) c++;
    }
    atomicAdd(&cnt_s, c);
    __syncthreads();
    if (threadIdx.x == 0) *flag = (cnt_s > 64) ? 1 : 0;
}

// ---------------- small buffers (biases, attn vecs) -> bf16 ws copies ---------
struct SCEnt { const void* s; bf16_t* d; int n; };
struct SCArgs { SCEnt e[16]; int cnt; };

__global__ __launch_bounds__(256)
void smallconv_k(SCArgs a, const int* __restrict__ flag)
{
    int isf = *flag;
    for (int k = 0; k < a.cnt; ++k) {
        int n = a.e[k].n;
        for (int i = threadIdx.x + blockIdx.x * 256; i < n; i += gridDim.x * 256) {
            float v = isf ? ((const float*)a.e[k].s)[i]
                          : (float)((const bf16_t*)a.e[k].s)[i];
            a.e[k].d[i] = (bf16_t)v;
        }
    }
}

// ---------------- fused dtype-aware transposes: WT[n][k] = W[eoff + k*256 + n]
struct TDesc { const void* W; size_t eoff; bf16_t* WT; int K; int tstart; };
struct TArgs { TDesc d[15]; int nd; };

__global__ __launch_bounds__(256)
void transpose_multi_k(TArgs ta, const int* __restrict__ flagp)
{
    __shared__ bf16_t tile[32][33];
    const int isf = *flagp;
    const int bx = blockIdx.x;
    int di = 0;
    while (di + 1 < ta.nd && bx >= ta.d[di + 1].tstart) ++di;
    const void* Wbase = ta.d[di].W;
    const size_t eoff = ta.d[di].eoff;
    bf16_t* WT        = ta.d[di].WT;
    const int K       = ta.d[di].K;
    const int ti      = bx - ta.d[di].tstart;
    const int tk      = K >> 5;            // tiles along K
    const int kb      = (ti % tk) * 32;
    const int nb      = (ti / tk) * 32;    // N = 256 fixed
    const int tx = threadIdx.x & 31, ty = threadIdx.x >> 5;
    #pragma unroll
    for (int rr = 0; rr < 4; ++rr) {
        int r = ty + rr * 8;
        size_t idx = eoff + (size_t)(kb + r) * 256 + nb + tx;
        tile[r][tx] = isf ? (bf16_t)((const float*)Wbase)[idx]
                          : ((const bf16_t*)Wbase)[idx];
    }
    __syncthreads();
    #pragma unroll
    for (int rr = 0; rr < 4; ++rr) {
        int r = ty + rr * 8;
        WT[(size_t)(nb + r) * K + kb + tx] = tile[tx][r];
    }
}

// ---------------- descriptor-fused bf16 MFMA GEMM -----------------------------
// 64x64 tiles. XCD-grouping swizzle: the 4 n-siblings of one A-panel are
// placed on the SAME XCD (bx & 7) within 24 dispatch slots of each other, so
// the panel is fetched from HBM once and sibling reads hit that XCD's L2.
// (Round-4 lesson: plain n-fastest order put siblings on 4 different XCDs
// with private L2s -> 4x HBM re-fetch, FETCH_SIZE 597 MB.)
// Every group count is a multiple of 8, so the decode below is bijective.
// 1-deep register prefetch: next K-step's A/B loads issue right after the
// first barrier, overlapping global latency with ds_read+MFMA+barrier.
#define BM 64
#define BN 64
#define BK 32
#define LST 40   // LDS row stride (elems); 80B rows keep b128 16B-aligned

struct GDesc {
    const void* A; const bf16_t* WT; const bf16_t* bias; bf16_t* out;
    int Kin, in_stride_b, in_off, rows_pb, a_is_ext, out_stride_b, out_off, mb_start;
};
struct GArgs { GDesc d[9]; int nd; };

__global__ __launch_bounds__(256)
void gemm_multi_k(GArgs ga, const int* __restrict__ flagp)
{
    __shared__ bf16_t As[BM * LST];
    __shared__ bf16_t Bs[BN * LST];

    // XCD-grouping decode: siblings j=0..3 of group g sit at bx = (g&7) + 8*(4*(g>>3)+j)
    const int bx  = blockIdx.x;
    const int xcd = bx & 7;
    const int w   = bx >> 3;
    const int mb  = (w >> 2) * 8 + xcd;      // m-block (descriptor space)
    const int n0  = (w & 3) * BN;            // n-offset

    int di = 0;
    while (di + 1 < ga.nd && mb >= ga.d[di + 1].mb_start) ++di;

    const void*   A        = ga.d[di].A;
    const bf16_t* WT       = ga.d[di].WT;
    const bf16_t* bias     = ga.d[di].bias;
    bf16_t*       out      = ga.d[di].out;
    const int Kin          = ga.d[di].Kin;
    const int in_stride_b  = ga.d[di].in_stride_b;
    const int in_off       = ga.d[di].in_off;
    const int rows_pb      = ga.d[di].rows_pb;
    const int out_stride_b = ga.d[di].out_stride_b;
    const int out_off      = ga.d[di].out_off;
    const int a_fp32 = ga.d[di].a_is_ext ? *flagp : 0;

    const int t  = threadIdx.x;
    const int m0 = (mb - ga.d[di].mb_start) * BM;

    const int s_row = t >> 2;          // 0..63
    const int s_col = (t & 3) * 8;     // 0,8,16,24

    const int g_row = m0 + s_row;
    const int b_idx = g_row / rows_pb;
    const int i_idx = g_row - b_idx * rows_pb;
    const size_t a_base = (size_t)(b_idx * in_stride_b + in_off + i_idx) * Kin + s_col;
    const bf16_t* w_ptr = WT + (size_t)(n0 + s_row) * Kin + s_col;

    const int wave = t >> 6;
    const int lane = t & 63;
    const int wr = (wave >> 1) * 32;
    const int wc = (wave & 1) * 32;
    const int lm = lane & 15;
    const int lk = (lane >> 4) * 8;

    floatx4 acc[2][2] = {};

    // ---- prologue: load K-step 0 into registers ----
    float4 f0, f1;
    bf16x8 avr, wvr;
    if (a_fp32) {
        const float* ap = (const float*)A + a_base;
        f0 = *(const float4*)ap;
        f1 = *(const float4*)(ap + 4);
    } else {
        avr = *(const bf16x8*)((const bf16_t*)A + a_base);
    }
    wvr = *(const bf16x8*)(w_ptr);

    for (int kk = 0; kk < Kin; kk += BK) {
        // convert + stage current step (regs were loaded last iteration)
        bf16x8 av;
        if (a_fp32) {
            av[0] = (bf16_t)f0.x; av[1] = (bf16_t)f0.y;
            av[2] = (bf16_t)f0.z; av[3] = (bf16_t)f0.w;
            av[4] = (bf16_t)f1.x; av[5] = (bf16_t)f1.y;
            av[6] = (bf16_t)f1.z; av[7] = (bf16_t)f1.w;
        } else {
            av = avr;
        }
        *(bf16x8*)(&As[s_row * LST + s_col]) = av;
        *(bf16x8*)(&Bs[s_row * LST + s_col]) = wvr;
        __syncthreads();

        // issue next step's global loads (latency hides under MFMA + barrier)
        if (kk + BK < Kin) {
            if (a_fp32) {
                const float* ap = (const float*)A + a_base + kk + BK;
                f0 = *(const float4*)ap;
                f1 = *(const float4*)(ap + 4);
            } else {
                avr = *(const bf16x8*)((const bf16_t*)A + a_base + kk + BK);
            }
            wvr = *(const bf16x8*)(w_ptr + kk + BK);
        }

        bf16x8 af0 = *(const bf16x8*)(&As[(wr      + lm) * LST + lk]);
        bf16x8 af1 = *(const bf16x8*)(&As[(wr + 16 + lm) * LST + lk]);
        bf16x8 bf0 = *(const bf16x8*)(&Bs[(wc      + lm) * LST + lk]);
        bf16x8 bf1 = *(const bf16x8*)(&Bs[(wc + 16 + lm) * LST + lk]);

        acc[0][0] = __builtin_amdgcn_mfma_f32_16x16x32_bf16(af0, bf0, acc[0][0], 0, 0, 0);
        acc[0][1] = __builtin_amdgcn_mfma_f32_16x16x32_bf16(af0, bf1, acc[0][1], 0, 0, 0);
        acc[1][0] = __builtin_amdgcn_mfma_f32_16x16x32_bf16(af1, bf0, acc[1][0], 0, 0, 0);
        acc[1][1] = __builtin_amdgcn_mfma_f32_16x16x32_bf16(af1, bf1, acc[1][1], 0, 0, 0);
        __syncthreads();
    }

    const int q = lane >> 4;
    #pragma unroll
    for (int i = 0; i < 2; ++i)
      #pragma unroll
      for (int j = 0; j < 2; ++j)
        #pragma unroll
        for (int r = 0; r < 4; ++r) {
            int row = m0 + wr + i * 16 + q * 4 + r;
            int col = n0 + wc + j * 16 + lm;
            int bb = row / rows_pb;
            int ii = row - bb * rows_pb;
            float v = acc[i][j][r];
            if (bias) v += (float)bias[col];
            out[(size_t)(bb * out_stride_b + out_off + ii) * DI + col] = (bf16_t)v;
        }
}

// ---------------- fused attention scores --------------------------------------
struct SDesc { const bf16_t* Wh; const bf16_t* as_; const bf16_t* ad_;
               float* s; float* d; int bstart; };
struct SArgs { SDesc e[3]; int nd; };

__global__ __launch_bounds__(256)
void scores_multi_k(SArgs sa)
{
    const int bx = blockIdx.x;
    int di = 0;
    while (di + 1 < sa.nd && bx >= sa.e[di + 1].bstart) ++di;
    const bf16_t* Wh    = sa.e[di].Wh;
    const bf16_t* a_src = sa.e[di].as_;
    const bf16_t* a_dst = sa.e[di].ad_;
    float* src = sa.e[di].s;
    float* dst = sa.e[di].d;

    int wid  = (bx - sa.e[di].bstart) * 4 + (threadIdx.x >> 6);
    int lane = threadIdx.x & 63;
    bf16x4 wv = *(const bf16x4*)(Wh + (size_t)wid * DI + lane * 4);
    bf16x4 sv = *(const bf16x4*)(a_src + lane * 4);
    bf16x4 dv = *(const bf16x4*)(a_dst + lane * 4);
    float s = 0.f, d = 0.f;
    #pragma unroll
    for (int i = 0; i < 4; ++i) {
        float w = (float)wv[i];
        s += w * (float)sv[i];
        d += w * (float)dv[i];
    }
    #pragma unroll
    for (int off = 32; off > 0; off >>= 1) {
        s += __shfl_down(s, off);
        d += __shfl_down(d, off);
    }
    if (lane == 0) { src[wid] = s; dst[wid] = d; }
}

// ---------------- hub aggregation helpers -------------------------------------
__device__ __forceinline__ float hub20(const bf16_t* __restrict__ Wh,
                                       const float* __restrict__ s,
                                       const float* __restrict__ d,
                                       int b, int c, int e)
{
    int base = b * 63 + 3 + c * 20;
    float ss = s[b * 63 + c];
    float ev[20], mx = -1e30f;
    #pragma unroll
    for (int i = 0; i < 20; ++i) { ev[i] = lrelu_f(ss + d[base + i]); mx = fmaxf(mx, ev[i]); }
    float sw = 0.f, acc = 0.f;
    #pragma unroll
    for (int i = 0; i < 20; ++i) {
        float w = expf(ev[i] - mx);
        sw  += w;
        acc += w * (float)Wh[(size_t)(base + i) * DI + e];
    }
    return acc / sw;
}

__device__ __forceinline__ float hub_tri(const bf16_t* __restrict__ Wh1,
                                         const float* __restrict__ s1,
                                         const float* __restrict__ d1,
                                         int b, int c, int e)
{
    int m0 = (c == 0) ? 1 : 0, m1 = (c == 2) ? 1 : 2;
    float ss = s1[b * 3 + c];
    float e0 = lrelu_f(ss + d1[b * 3 + m0]);
    float e1 = lrelu_f(ss + d1[b * 3 + m1]);
    float mx = fmaxf(e0, e1);
    float w0 = expf(e0 - mx), w1 = expf(e1 - mx);
    return (w0 * (float)Wh1[(size_t)(b * 3 + m0) * DI + e] +
            w1 * (float)Wh1[(size_t)(b * 3 + m1) * DI + e]) / (w0 + w1);
}

// ---------------- stage aggregations ------------------------------------------
__global__ __launch_bounds__(256)
void agg1_k(const bf16_t* __restrict__ Wh1, const float* __restrict__ s1,
            const float* __restrict__ d1, bf16_t* __restrict__ nodes2)
{
    int blk = blockIdx.x;
    int b = blk / 3, n = blk - b * 3;
    int e = threadIdx.x;
    float v = hub_tri(Wh1, s1, d1, b, n, e);
    nodes2[(size_t)(b * 63 + n) * DI + e] = (bf16_t)elu_f(v);
}

__global__ __launch_bounds__(256)
void agg2_k(const bf16_t* __restrict__ Wh1, const bf16_t* __restrict__ Wh2,
            const float* __restrict__ s1, const float* __restrict__ d1,
            const float* __restrict__ s2, const float* __restrict__ d2,
            bf16_t* __restrict__ nodes3)
{
    int blk = blockIdx.x;
    int b = blk / 63, n = blk - b * 63;
    int e = threadIdx.x;
    float v;
    if (n >= 3) {
        int c = (n - 3) / 20;
        v = (float)Wh2[(size_t)(b * 63 + c) * DI + e];
    } else {
        v = hub_tri(Wh1, s1, d1, b, n, e) + hub20(Wh2, s2, d2, b, n, e);
    }
    nodes3[(size_t)(b * 123 + n) * DI + e] = (bf16_t)elu_f(v);
}

__global__ __launch_bounds__(256)
void agg3_k(const bf16_t* __restrict__ Wh1, const bf16_t* __restrict__ Wh2,
            const bf16_t* __restrict__ Wh3,
            const float* __restrict__ s1, const float* __restrict__ d1,
            const float* __restrict__ s2, const float* __restrict__ d2,
            const float* __restrict__ s3, const float* __restrict__ d3,
            void* __restrict__ out, const int* __restrict__ flagp)
{
    int isf = *flagp;
    int blk = blockIdx.x;
    int b = blk / 123, n = blk - b * 123;
    int e = threadIdx.x;
    float v;
    if (n >= 63) {
        int c = (n - 63) / 20;
        v = (float)Wh3[(size_t)(b * 63 + c) * DI + e];
    } else if (n >= 3) {
        int c = (n - 3) / 20;
        v = (float)Wh2[(size_t)(b * 63 + c) * DI + e];
    } else {
        v = hub_tri(Wh1, s1, d1, b, n, e)
          + hub20(Wh2, s2, d2, b, n, e)
          + hub20(Wh3, s3, d3, b, n, e);
    }
    float r = elu_f(v);
    size_t oi = (size_t)(b * 123 + n) * DI + e;
    if (isf) ((float*)out)[oi] = r;
    else     ((bf16_t*)out)[oi] = (bf16_t)r;
}

// ------------------------------------------------------------------------------
extern "C" void kernel_launch(void* const* d_in, const int* in_sizes, int n_in,
                              void* d_out, int out_size, void* d_ws, size_t ws_size,
                              hipStream_t stream)
{
    (void)in_sizes; (void)n_in; (void)out_size; (void)ws_size;
    const void *scene_tv=d_in[0], *face_tv=d_in[1], *text_tv=d_in[2],
               *scene_refs=d_in[3], *face_refs=d_in[4], *text_refs=d_in[5],
               *scene_ra=d_in[6], *face_ra=d_in[7], *text_ra=d_in[8],
               *Ws1=d_in[9],  *bs1=d_in[10], *Wf1=d_in[11], *bf1=d_in[12],
               *Wt1=d_in[13], *bt1=d_in[14],
               *G1W=d_in[15], *G1as=d_in[16], *G1ad=d_in[17],
               *Ws2=d_in[18], *bs2=d_in[19], *Wf2=d_in[20], *bf2=d_in[21],
               *Wt2=d_in[22], *bt2=d_in[23],
               *G2W=d_in[24], *G2as=d_in[25], *G2ad=d_in[26],
               *Ws3=d_in[27], *bs3=d_in[28], *Wf3=d_in[29], *bf3=d_in[30],
               *Wt3=d_in[31], *bt3=d_in[32],
               *G3W=d_in[33], *G3as=d_in[34], *G3ad=d_in[35];

    char* p = (char*)d_ws;
    auto carveB = [&](size_t elems) -> bf16_t* { bf16_t* r = (bf16_t*)p; p += ((elems*2 + 255) & ~(size_t)255); return r; };
    auto carveF = [&](size_t elems) -> float*  { float*  r = (float*)p;  p += ((elems*4 + 255) & ~(size_t)255); return r; };
    auto carveI = [&]() -> int* { int* r = (int*)p; p += 256; return r; };

    int* flag = carveI();

    bf16_t* Ws1T = carveB(1024*256); bf16_t* Wf1T = carveB(1024*256); bf16_t* Wt1T = carveB(2048*256);
    bf16_t* Ws2T = carveB(1024*256); bf16_t* Wf2T = carveB(1024*256); bf16_t* Wt2T = carveB(2048*256);
    bf16_t* Ws3T = carveB(1024*256); bf16_t* Wf3T = carveB(1024*256); bf16_t* Wt3T = carveB(1024*256);
    bf16_t* G1WT = carveB(256*256);
    bf16_t* G2WT = carveB(2*256*256);
    bf16_t* G3WT = carveB(3*256*256);

    bf16_t* cb[9];
    for (int i = 0; i < 9; ++i) cb[i] = carveB(256);
    bf16_t* a1s = carveB(256); bf16_t* a1d = carveB(256);
    bf16_t* a2s = carveB(512); bf16_t* a2d = carveB(512);
    bf16_t* a3s = carveB(768); bf16_t* a3d = carveB(768);

    bf16_t* nodes1 = carveB((size_t)NB*3*DI);
    bf16_t* nodes2 = carveB((size_t)NB*63*DI);
    bf16_t* nodes3 = carveB((size_t)NB*123*DI);
    bf16_t* Wh1    = carveB((size_t)NB*3*DI);
    bf16_t* Wh2    = carveB((size_t)NB*63*DI);
    bf16_t* Wh3    = carveB((size_t)NB*63*DI);
    float* s1s = carveF(NB*3);  float* s1d = carveF(NB*3);
    float* s2s = carveF(NB*63); float* s2d = carveF(NB*63);
    float* s3s = carveF(NB*63); float* s3d = carveF(NB*63);

    detect_k<<<1, 256, 0, stream>>>(Ws1, flag);

    SCArgs sca;
    const void* ssrc[15] = { bs1, bf1, bt1, bs2, bf2, bt2, bs3, bf3, bt3,
                             G1as, G1ad, G2as, G2ad, G3as, G3ad };
    bf16_t* sdst[15] = { cb[0],cb[1],cb[2],cb[3],cb[4],cb[5],cb[6],cb[7],cb[8],
                         a1s, a1d, a2s, a2d, a3s, a3d };
    int sn[15] = { 256,256,256,256,256,256,256,256,256, 256,256,512,512,768,768 };
    for (int i = 0; i < 15; ++i) { sca.e[i].s = ssrc[i]; sca.e[i].d = sdst[i]; sca.e[i].n = sn[i]; }
    sca.cnt = 15;
    smallconv_k<<<1, 256, 0, stream>>>(sca, flag);

    // ---- all 15 weight transposes in one launch ----
    TArgs ta; ta.nd = 0; int tcum = 0;
    auto addT = [&](const void* W, size_t eoff, bf16_t* WT, int K) {
        ta.d[ta.nd].W = W; ta.d[ta.nd].eoff = eoff; ta.d[ta.nd].WT = WT;
        ta.d[ta.nd].K = K; ta.d[ta.nd].tstart = tcum;
        tcum += (K / 32) * 8; ta.nd++;
    };
    addT(Ws1, 0, Ws1T, 1024); addT(Wf1, 0, Wf1T, 1024); addT(Wt1, 0, Wt1T, 2048);
    addT(Ws2, 0, Ws2T, 1024); addT(Wf2, 0, Wf2T, 1024); addT(Wt2, 0, Wt2T, 2048);
    addT(Ws3, 0, Ws3T, 1024); addT(Wf3, 0, Wf3T, 1024); addT(Wt3, 0, Wt3T, 1024);
    addT(G1W, 0,      G1WT,          256);
    addT(G2W, 0,      G2WT,          256); addT(G2W, 65536,  G2WT + 65536,  256);
    addT(G3W, 0,      G3WT,          256); addT(G3W, 65536,  G3WT + 65536,  256);
    addT(G3W, 131072, G3WT + 131072, 256);
    transpose_multi_k<<<tcum, 256, 0, stream>>>(ta, flag);

    auto addG = [](GArgs& A, int& cum, const void* Ain, int Kin, int isb, int ioff,
                   int rpb, int ext, const bf16_t* WT, const bf16_t* bias,
                   bf16_t* out, int osb, int ooff, int M) {
        GDesc& g = A.d[A.nd];
        g.A = Ain; g.WT = WT; g.bias = bias; g.out = out;
        g.Kin = Kin; g.in_stride_b = isb; g.in_off = ioff; g.rows_pb = rpb;
        g.a_is_ext = ext; g.out_stride_b = osb; g.out_off = ooff; g.mb_start = cum;
        cum += M / 64; A.nd++;
    };

    // ---- ALL nine input projections (no inter-dependencies) in ONE launch ----
    GArgs pg; pg.nd = 0; int pc = 0;
    addG(pg, pc, scene_tv,   1024,  1, 0,  1, 1, Ws1T, cb[0], nodes1,   3,   0, NB);
    addG(pg, pc, face_tv,    1024,  1, 0,  1, 1, Wf1T, cb[1], nodes1,   3,   1, NB);
    addG(pg, pc, text_tv,    2048,  1, 0,  1, 1, Wt1T, cb[2], nodes1,   3,   2, NB);
    addG(pg, pc, scene_refs, 1024, 20, 0, 20, 1, Ws2T, cb[3], nodes2,  63,   3, NB*20);
    addG(pg, pc, face_refs,  1024, 20, 0, 20, 1, Wf2T, cb[4], nodes2,  63,  23, NB*20);
    addG(pg, pc, text_refs,  2048, 20, 0, 20, 1, Wt2T, cb[5], nodes2,  63,  43, NB*20);
    addG(pg, pc, scene_ra,   1024, 20, 0, 20, 1, Ws3T, cb[6], nodes3, 123,  63, NB*20);
    addG(pg, pc, face_ra,    1024, 20, 0, 20, 1, Wf3T, cb[7], nodes3, 123,  83, NB*20);
    addG(pg, pc, text_ra,    1024, 20, 0, 20, 1, Wt3T, cb[8], nodes3, 123, 103, NB*20);
    gemm_multi_k<<<pc * 4, 256, 0, stream>>>(pg, flag);

    // -------- stage 1 --------
    GArgs g1; g1.nd = 0; int c1 = 0;
    addG(g1, c1, nodes1, 256, 3, 0, 3, 0, G1WT, nullptr, Wh1, 3, 0, NB*3);
    gemm_multi_k<<<c1 * 4, 256, 0, stream>>>(g1, flag);

    SArgs s1a; s1a.nd = 1;
    s1a.e[0].Wh = Wh1; s1a.e[0].as_ = a1s; s1a.e[0].ad_ = a1d;
    s1a.e[0].s = s1s; s1a.e[0].d = s1d; s1a.e[0].bstart = 0;
    scores_multi_k<<<NB*3/4, 256, 0, stream>>>(s1a);
    agg1_k<<<NB*3, 256, 0, stream>>>(Wh1, s1s, s1d, nodes2);

    // -------- stage 2 --------
    GArgs g2; g2.nd = 0; int c2 = 0;
    addG(g2, c2, nodes2, 256, 63, 0,  3, 0, G2WT,         nullptr, Wh1,  3, 0, NB*3);
    addG(g2, c2, nodes2, 256, 63, 0, 63, 0, G2WT + 65536, nullptr, Wh2, 63, 0, NB*63);
    gemm_multi_k<<<c2 * 4, 256, 0, stream>>>(g2, flag);

    SArgs s2a; s2a.nd = 2;
    s2a.e[0].Wh = Wh1; s2a.e[0].as_ = a2s;       s2a.e[0].ad_ = a2d;
    s2a.e[0].s = s1s;  s2a.e[0].d = s1d;         s2a.e[0].bstart = 0;
    s2a.e[1].Wh = Wh2; s2a.e[1].as_ = a2s + 256; s2a.e[1].ad_ = a2d + 256;
    s2a.e[1].s = s2s;  s2a.e[1].d = s2d;         s2a.e[1].bstart = NB*3/4;
    scores_multi_k<<<NB*3/4 + NB*63/4, 256, 0, stream>>>(s2a);
    agg2_k<<<NB*63, 256, 0, stream>>>(Wh1, Wh2, s1s, s1d, s2s, s2d, nodes3);

    // -------- stage 3 --------
    GArgs g3; g3.nd = 0; int c3 = 0;
    addG(g3, c3, nodes3, 256, 123,  0,  3, 0, G3WT,          nullptr, Wh1,  3, 0, NB*3);
    addG(g3, c3, nodes3, 256, 123,  0, 63, 0, G3WT + 65536,  nullptr, Wh2, 63, 0, NB*63);
    addG(g3, c3, nodes3, 256, 123,  0,  3, 0, G3WT + 131072, nullptr, Wh3, 63, 0, NB*3);
    addG(g3, c3, nodes3, 256, 123, 63, 60, 0, G3WT + 131072, nullptr, Wh3, 63, 3, NB*60);
    gemm_multi_k<<<c3 * 4, 256, 0, stream>>>(g3, flag);

    SArgs s3a; s3a.nd = 3;
    s3a.e[0].Wh = Wh1; s3a.e[0].as_ = a3s;       s3a.e[0].ad_ = a3d;
    s3a.e[0].s = s1s;  s3a.e[0].d = s1d;         s3a.e[0].bstart = 0;
    s3a.e[1].Wh = Wh2; s3a.e[1].as_ = a3s + 256; s3a.e[1].ad_ = a3d + 256;
    s3a.e[1].s = s2s;  s3a.e[1].d = s2d;         s3a.e[1].bstart = NB*3/4;
    s3a.e[2].Wh = Wh3; s3a.e[2].as_ = a3s + 512; s3a.e[2].ad_ = a3d + 512;
    s3a.e[2].s = s3s;  s3a.e[2].d = s3d;         s3a.e[2].bstart = NB*3/4 + NB*63/4;
    scores_multi_k<<<NB*3/4 + 2*(NB*63/4), 256, 0, stream>>>(s3a);
    agg3_k<<<NB*123, 256, 0, stream>>>(Wh1, Wh2, Wh3, s1s, s1d, s2s, s2d, s3s, s3d,
                                       d_out, flag);
}

// Round 6
// 588.665 us; speedup vs baseline: 1.0981x; 1.0247x over previous
//
#include <hip/hip_runtime.h>
#include <hip/hip_bf16.h>
#include <math.h>

typedef __bf16 bf16_t;
typedef __bf16 bf16x8 __attribute__((ext_vector_type(8)));
typedef __bf16 bf16x4 __attribute__((ext_vector_type(4)));
typedef float  floatx4 __attribute__((ext_vector_type(4)));

#define NB 512      // batch
#define DI 256      // feature dim

__device__ __forceinline__ float lrelu_f(float x){ return x >= 0.f ? x : 0.2f*x; }
__device__ __forceinline__ float elu_f(float x){ return x > 0.f ? x : expm1f(x); }

// ---------------- dtype probe: fp32 (flag=1) vs bf16 (flag=0) -----------------
__global__ __launch_bounds__(256)
void detect_k(const void* __restrict__ probe, int* __restrict__ flag)
{
    __shared__ int cnt_s;
    if (threadIdx.x == 0) cnt_s = 0;
    __syncthreads();
    const unsigned short* u = (const unsigned short*)probe;
    int c = 0;
    for (int i = threadIdx.x; i < 16384; i += 256) {
        int e = (u[i] >> 7) & 0xFF;
        if (e >= 0x90) c++;
    }
    atomicAdd(&cnt_s, c);
    __syncthreads();
    if (threadIdx.x == 0) *flag = (cnt_s > 64) ? 1 : 0;
}

// ---------------- small buffers (biases, attn vecs) -> bf16 ws copies ---------
struct SCEnt { const void* s; bf16_t* d; int n; };
struct SCArgs { SCEnt e[16]; int cnt; };

__global__ __launch_bounds__(256)
void smallconv_k(SCArgs a, const int* __restrict__ flag)
{
    int isf = *flag;
    for (int k = 0; k < a.cnt; ++k) {
        int n = a.e[k].n;
        for (int i = threadIdx.x + blockIdx.x * 256; i < n; i += gridDim.x * 256) {
            float v = isf ? ((const float*)a.e[k].s)[i]
                          : (float)((const bf16_t*)a.e[k].s)[i];
            a.e[k].d[i] = (bf16_t)v;
        }
    }
}

// ---------------- fused dtype-aware transposes: WT[n][k] = W[eoff + k*256 + n]
struct TDesc { const void* W; size_t eoff; bf16_t* WT; int K; int tstart; };
struct TArgs { TDesc d[15]; int nd; };

__global__ __launch_bounds__(256)
void transpose_multi_k(TArgs ta, const int* __restrict__ flagp)
{
    __shared__ bf16_t tile[32][33];
    const int isf = *flagp;
    const int bx = blockIdx.x;
    int di = 0;
    while (di + 1 < ta.nd && bx >= ta.d[di + 1].tstart) ++di;
    const void* Wbase = ta.d[di].W;
    const size_t eoff = ta.d[di].eoff;
    bf16_t* WT        = ta.d[di].WT;
    const int K       = ta.d[di].K;
    const int ti      = bx - ta.d[di].tstart;
    const int tk      = K >> 5;            // tiles along K
    const int kb      = (ti % tk) * 32;
    const int nb      = (ti / tk) * 32;    // N = 256 fixed
    const int tx = threadIdx.x & 31, ty = threadIdx.x >> 5;
    #pragma unroll
    for (int rr = 0; rr < 4; ++rr) {
        int r = ty + rr * 8;
        size_t idx = eoff + (size_t)(kb + r) * 256 + nb + tx;
        tile[r][tx] = isf ? (bf16_t)((const float*)Wbase)[idx]
                          : ((const bf16_t*)Wbase)[idx];
    }
    __syncthreads();
    #pragma unroll
    for (int rr = 0; rr < 4; ++rr) {
        int r = ty + rr * 8;
        WT[(size_t)(nb + r) * K + kb + tx] = tile[tx][r];
    }
}

// ---------------- descriptor-fused bf16 MFMA GEMM -----------------------------
// 128x128 tiles (m93-style): each wave owns a 64x64 quadrant, 16 MFMAs + 8
// ds_read_b128 per K-step between one barrier pair -> 4x more work per barrier
// than the old 64x64 tile (round-5 limiter). 2 n-blocks per tile halves A
// re-reads. XCD-grouping swizzle kept: both n-siblings of an A-panel land on
// the same XCD within 16 dispatch slots; grid padded to a multiple of 8 groups
// (early-exit blocks) so the decode stays bijective for any group count.
// 1-deep register prefetch of next K-step's A/B.
#define BM 128
#define BN 128
#define BK 32
#define LST 40   // LDS row stride (elems); 80B rows keep b128 16B-aligned

struct GDesc {
    const void* A; const bf16_t* WT; const bf16_t* bias; bf16_t* out;
    int Kin, in_stride_b, in_off, rows_pb, a_is_ext, out_stride_b, out_off, mb_start;
};
struct GArgs { GDesc d[9]; int nd; int total_mb; };

__global__ __launch_bounds__(256)
void gemm_multi_k(GArgs ga, const int* __restrict__ flagp)
{
    __shared__ bf16_t As[BM * LST];   // 10240 B
    __shared__ bf16_t Bs[BN * LST];   // 10240 B

    // decode: group g (m-panel) pinned to XCD bx&7; n-sibling = (w&1)
    const int bx  = blockIdx.x;
    const int xcd = bx & 7;
    const int w   = bx >> 3;
    const int g   = (w >> 1) * 8 + xcd;
    const int n0  = (w & 1) * BN;
    if (g >= ga.total_mb) return;          // padding block (uniform exit, pre-barrier)

    int di = 0;
    while (di + 1 < ga.nd && g >= ga.d[di + 1].mb_start) ++di;

    const void*   A        = ga.d[di].A;
    const bf16_t* WT       = ga.d[di].WT;
    const bf16_t* bias     = ga.d[di].bias;
    bf16_t*       out      = ga.d[di].out;
    const int Kin          = ga.d[di].Kin;
    const int in_stride_b  = ga.d[di].in_stride_b;
    const int in_off       = ga.d[di].in_off;
    const int rows_pb      = ga.d[di].rows_pb;
    const int out_stride_b = ga.d[di].out_stride_b;
    const int out_off      = ga.d[di].out_off;
    const int a_fp32 = ga.d[di].a_is_ext ? *flagp : 0;

    const int t  = threadIdx.x;
    const int m0 = (g - ga.d[di].mb_start) * BM;

    // staging: thread t covers row t>>1 (0..127), 16-elem chunk (t&1)*16
    const int s_row = t >> 1;
    const int s_col = (t & 1) * 16;

    const int g_row = m0 + s_row;
    const int b_idx = g_row / rows_pb;
    const int i_idx = g_row - b_idx * rows_pb;
    const size_t a_base = (size_t)(b_idx * in_stride_b + in_off + i_idx) * Kin + s_col;
    const bf16_t* w_ptr = WT + (size_t)(n0 + s_row) * Kin + s_col;

    const int wave = t >> 6;
    const int lane = t & 63;
    const int wr = (wave >> 1) * 64;
    const int wc = (wave & 1) * 64;
    const int lm = lane & 15;
    const int lk = (lane >> 4) * 8;

    floatx4 acc[4][4] = {};

    // ---- prologue: K-step 0 into registers ----
    float4 fA0, fA1, fA2, fA3;
    bf16x8 aA0, aA1, wB0, wB1;
    if (a_fp32) {
        const float* ap = (const float*)A + a_base;
        fA0 = ((const float4*)ap)[0]; fA1 = ((const float4*)ap)[1];
        fA2 = ((const float4*)ap)[2]; fA3 = ((const float4*)ap)[3];
    } else {
        aA0 = *(const bf16x8*)((const bf16_t*)A + a_base);
        aA1 = *(const bf16x8*)((const bf16_t*)A + a_base + 8);
    }
    wB0 = *(const bf16x8*)(w_ptr);
    wB1 = *(const bf16x8*)(w_ptr + 8);

    for (int kk = 0; kk < Kin; kk += BK) {
        bf16x8 av0, av1;
        if (a_fp32) {
            av0[0] = (bf16_t)fA0.x; av0[1] = (bf16_t)fA0.y;
            av0[2] = (bf16_t)fA0.z; av0[3] = (bf16_t)fA0.w;
            av0[4] = (bf16_t)fA1.x; av0[5] = (bf16_t)fA1.y;
            av0[6] = (bf16_t)fA1.z; av0[7] = (bf16_t)fA1.w;
            av1[0] = (bf16_t)fA2.x; av1[1] = (bf16_t)fA2.y;
            av1[2] = (bf16_t)fA2.z; av1[3] = (bf16_t)fA2.w;
            av1[4] = (bf16_t)fA3.x; av1[5] = (bf16_t)fA3.y;
            av1[6] = (bf16_t)fA3.z; av1[7] = (bf16_t)fA3.w;
        } else {
            av0 = aA0; av1 = aA1;
        }
        *(bf16x8*)(&As[s_row * LST + s_col])     = av0;
        *(bf16x8*)(&As[s_row * LST + s_col + 8]) = av1;
        *(bf16x8*)(&Bs[s_row * LST + s_col])     = wB0;
        *(bf16x8*)(&Bs[s_row * LST + s_col + 8]) = wB1;
        __syncthreads();

        // issue next step's global loads; latency hides under 16 MFMAs + barrier
        if (kk + BK < Kin) {
            if (a_fp32) {
                const float* ap = (const float*)A + a_base + kk + BK;
                fA0 = ((const float4*)ap)[0]; fA1 = ((const float4*)ap)[1];
                fA2 = ((const float4*)ap)[2]; fA3 = ((const float4*)ap)[3];
            } else {
                aA0 = *(const bf16x8*)((const bf16_t*)A + a_base + kk + BK);
                aA1 = *(const bf16x8*)((const bf16_t*)A + a_base + kk + BK + 8);
            }
            wB0 = *(const bf16x8*)(w_ptr + kk + BK);
            wB1 = *(const bf16x8*)(w_ptr + kk + BK + 8);
        }

        bf16x8 af[4], bv[4];
        #pragma unroll
        for (int i = 0; i < 4; ++i) {
            af[i] = *(const bf16x8*)(&As[(wr + i * 16 + lm) * LST + lk]);
            bv[i] = *(const bf16x8*)(&Bs[(wc + i * 16 + lm) * LST + lk]);
        }
        #pragma unroll
        for (int i = 0; i < 4; ++i)
          #pragma unroll
          for (int j = 0; j < 4; ++j)
            acc[i][j] = __builtin_amdgcn_mfma_f32_16x16x32_bf16(af[i], bv[j], acc[i][j], 0, 0, 0);
        __syncthreads();
    }

    const int q = lane >> 4;
    #pragma unroll
    for (int i = 0; i < 4; ++i)
      #pragma unroll
      for (int j = 0; j < 4; ++j)
        #pragma unroll
        for (int r = 0; r < 4; ++r) {
            int row = m0 + wr + i * 16 + q * 4 + r;
            int col = n0 + wc + j * 16 + lm;
            int bb = row / rows_pb;
            int ii = row - bb * rows_pb;
            float v = acc[i][j][r];
            if (bias) v += (float)bias[col];
            out[(size_t)(bb * out_stride_b + out_off + ii) * DI + col] = (bf16_t)v;
        }
}

// ---------------- fused attention scores --------------------------------------
struct SDesc { const bf16_t* Wh; const bf16_t* as_; const bf16_t* ad_;
               float* s; float* d; int bstart; };
struct SArgs { SDesc e[3]; int nd; };

__global__ __launch_bounds__(256)
void scores_multi_k(SArgs sa)
{
    const int bx = blockIdx.x;
    int di = 0;
    while (di + 1 < sa.nd && bx >= sa.e[di + 1].bstart) ++di;
    const bf16_t* Wh    = sa.e[di].Wh;
    const bf16_t* a_src = sa.e[di].as_;
    const bf16_t* a_dst = sa.e[di].ad_;
    float* src = sa.e[di].s;
    float* dst = sa.e[di].d;

    int wid  = (bx - sa.e[di].bstart) * 4 + (threadIdx.x >> 6);
    int lane = threadIdx.x & 63;
    bf16x4 wv = *(const bf16x4*)(Wh + (size_t)wid * DI + lane * 4);
    bf16x4 sv = *(const bf16x4*)(a_src + lane * 4);
    bf16x4 dv = *(const bf16x4*)(a_dst + lane * 4);
    float s = 0.f, d = 0.f;
    #pragma unroll
    for (int i = 0; i < 4; ++i) {
        float w = (float)wv[i];
        s += w * (float)sv[i];
        d += w * (float)dv[i];
    }
    #pragma unroll
    for (int off = 32; off > 0; off >>= 1) {
        s += __shfl_down(s, off);
        d += __shfl_down(d, off);
    }
    if (lane == 0) { src[wid] = s; dst[wid] = d; }
}

// ---------------- hub aggregation helpers -------------------------------------
__device__ __forceinline__ float hub20(const bf16_t* __restrict__ Wh,
                                       const float* __restrict__ s,
                                       const float* __restrict__ d,
                                       int b, int c, int e)
{
    int base = b * 63 + 3 + c * 20;
    float ss = s[b * 63 + c];
    float ev[20], mx = -1e30f;
    #pragma unroll
    for (int i = 0; i < 20; ++i) { ev[i] = lrelu_f(ss + d[base + i]); mx = fmaxf(mx, ev[i]); }
    float sw = 0.f, acc = 0.f;
    #pragma unroll
    for (int i = 0; i < 20; ++i) {
        float w = expf(ev[i] - mx);
        sw  += w;
        acc += w * (float)Wh[(size_t)(base + i) * DI + e];
    }
    return acc / sw;
}

__device__ __forceinline__ float hub_tri(const bf16_t* __restrict__ Wh1,
                                         const float* __restrict__ s1,
                                         const float* __restrict__ d1,
                                         int b, int c, int e)
{
    int m0 = (c == 0) ? 1 : 0, m1 = (c == 2) ? 1 : 2;
    float ss = s1[b * 3 + c];
    float e0 = lrelu_f(ss + d1[b * 3 + m0]);
    float e1 = lrelu_f(ss + d1[b * 3 + m1]);
    float mx = fmaxf(e0, e1);
    float w0 = expf(e0 - mx), w1 = expf(e1 - mx);
    return (w0 * (float)Wh1[(size_t)(b * 3 + m0) * DI + e] +
            w1 * (float)Wh1[(size_t)(b * 3 + m1) * DI + e]) / (w0 + w1);
}

// ---------------- stage aggregations ------------------------------------------
__global__ __launch_bounds__(256)
void agg1_k(const bf16_t* __restrict__ Wh1, const float* __restrict__ s1,
            const float* __restrict__ d1, bf16_t* __restrict__ nodes2)
{
    int blk = blockIdx.x;
    int b = blk / 3, n = blk - b * 3;
    int e = threadIdx.x;
    float v = hub_tri(Wh1, s1, d1, b, n, e);
    nodes2[(size_t)(b * 63 + n) * DI + e] = (bf16_t)elu_f(v);
}

__global__ __launch_bounds__(256)
void agg2_k(const bf16_t* __restrict__ Wh1, const bf16_t* __restrict__ Wh2,
            const float* __restrict__ s1, const float* __restrict__ d1,
            const float* __restrict__ s2, const float* __restrict__ d2,
            bf16_t* __restrict__ nodes3)
{
    int blk = blockIdx.x;
    int b = blk / 63, n = blk - b * 63;
    int e = threadIdx.x;
    float v;
    if (n >= 3) {
        int c = (n - 3) / 20;
        v = (float)Wh2[(size_t)(b * 63 + c) * DI + e];
    } else {
        v = hub_tri(Wh1, s1, d1, b, n, e) + hub20(Wh2, s2, d2, b, n, e);
    }
    nodes3[(size_t)(b * 123 + n) * DI + e] = (bf16_t)elu_f(v);
}

__global__ __launch_bounds__(256)
void agg3_k(const bf16_t* __restrict__ Wh1, const bf16_t* __restrict__ Wh2,
            const bf16_t* __restrict__ Wh3,
            const float* __restrict__ s1, const float* __restrict__ d1,
            const float* __restrict__ s2, const float* __restrict__ d2,
            const float* __restrict__ s3, const float* __restrict__ d3,
            void* __restrict__ out, const int* __restrict__ flagp)
{
    int isf = *flagp;
    int blk = blockIdx.x;
    int b = blk / 123, n = blk - b * 123;
    int e = threadIdx.x;
    float v;
    if (n >= 63) {
        int c = (n - 63) / 20;
        v = (float)Wh3[(size_t)(b * 63 + c) * DI + e];
    } else if (n >= 3) {
        int c = (n - 3) / 20;
        v = (float)Wh2[(size_t)(b * 63 + c) * DI + e];
    } else {
        v = hub_tri(Wh1, s1, d1, b, n, e)
          + hub20(Wh2, s2, d2, b, n, e)
          + hub20(Wh3, s3, d3, b, n, e);
    }
    float r = elu_f(v);
    size_t oi = (size_t)(b * 123 + n) * DI + e;
    if (isf) ((float*)out)[oi] = r;
    else     ((bf16_t*)out)[oi] = (bf16_t)r;
}

// ------------------------------------------------------------------------------
extern "C" void kernel_launch(void* const* d_in, const int* in_sizes, int n_in,
                              void* d_out, int out_size, void* d_ws, size_t ws_size,
                              hipStream_t stream)
{
    (void)in_sizes; (void)n_in; (void)out_size; (void)ws_size;
    const void *scene_tv=d_in[0], *face_tv=d_in[1], *text_tv=d_in[2],
               *scene_refs=d_in[3], *face_refs=d_in[4], *text_refs=d_in[5],
               *scene_ra=d_in[6], *face_ra=d_in[7], *text_ra=d_in[8],
               *Ws1=d_in[9],  *bs1=d_in[10], *Wf1=d_in[11], *bf1=d_in[12],
               *Wt1=d_in[13], *bt1=d_in[14],
               *G1W=d_in[15], *G1as=d_in[16], *G1ad=d_in[17],
               *Ws2=d_in[18], *bs2=d_in[19], *Wf2=d_in[20], *bf2=d_in[21],
               *Wt2=d_in[22], *bt2=d_in[23],
               *G2W=d_in[24], *G2as=d_in[25], *G2ad=d_in[26],
               *Ws3=d_in[27], *bs3=d_in[28], *Wf3=d_in[29], *bf3=d_in[30],
               *Wt3=d_in[31], *bt3=d_in[32],
               *G3W=d_in[33], *G3as=d_in[34], *G3ad=d_in[35];

    char* p = (char*)d_ws;
    auto carveB = [&](size_t elems) -> bf16_t* { bf16_t* r = (bf16_t*)p; p += ((elems*2 + 255) & ~(size_t)255); return r; };
    auto carveF = [&](size_t elems) -> float*  { float*  r = (float*)p;  p += ((elems*4 + 255) & ~(size_t)255); return r; };
    auto carveI = [&]() -> int* { int* r = (int*)p; p += 256; return r; };

    int* flag = carveI();

    bf16_t* Ws1T = carveB(1024*256); bf16_t* Wf1T = carveB(1024*256); bf16_t* Wt1T = carveB(2048*256);
    bf16_t* Ws2T = carveB(1024*256); bf16_t* Wf2T = carveB(1024*256); bf16_t* Wt2T = carveB(2048*256);
    bf16_t* Ws3T = carveB(1024*256); bf16_t* Wf3T = carveB(1024*256); bf16_t* Wt3T = carveB(1024*256);
    bf16_t* G1WT = carveB(256*256);
    bf16_t* G2WT = carveB(2*256*256);
    bf16_t* G3WT = carveB(3*256*256);

    bf16_t* cb[9];
    for (int i = 0; i < 9; ++i) cb[i] = carveB(256);
    bf16_t* a1s = carveB(256); bf16_t* a1d = carveB(256);
    bf16_t* a2s = carveB(512); bf16_t* a2d = carveB(512);
    bf16_t* a3s = carveB(768); bf16_t* a3d = carveB(768);

    bf16_t* nodes1 = carveB((size_t)NB*3*DI);
    bf16_t* nodes2 = carveB((size_t)NB*63*DI);
    bf16_t* nodes3 = carveB((size_t)NB*123*DI);
    bf16_t* Wh1    = carveB((size_t)NB*3*DI);
    bf16_t* Wh2    = carveB((size_t)NB*63*DI);
    bf16_t* Wh3    = carveB((size_t)NB*63*DI);
    float* s1s = carveF(NB*3);  float* s1d = carveF(NB*3);
    float* s2s = carveF(NB*63); float* s2d = carveF(NB*63);
    float* s3s = carveF(NB*63); float* s3d = carveF(NB*63);

    detect_k<<<1, 256, 0, stream>>>(Ws1, flag);

    SCArgs sca;
    const void* ssrc[15] = { bs1, bf1, bt1, bs2, bf2, bt2, bs3, bf3, bt3,
                             G1as, G1ad, G2as, G2ad, G3as, G3ad };
    bf16_t* sdst[15] = { cb[0],cb[1],cb[2],cb[3],cb[4],cb[5],cb[6],cb[7],cb[8],
                         a1s, a1d, a2s, a2d, a3s, a3d };
    int sn[15] = { 256,256,256,256,256,256,256,256,256, 256,256,512,512,768,768 };
    for (int i = 0; i < 15; ++i) { sca.e[i].s = ssrc[i]; sca.e[i].d = sdst[i]; sca.e[i].n = sn[i]; }
    sca.cnt = 15;
    smallconv_k<<<1, 256, 0, stream>>>(sca, flag);

    // ---- all 15 weight transposes in one launch ----
    TArgs ta; ta.nd = 0; int tcum = 0;
    auto addT = [&](const void* W, size_t eoff, bf16_t* WT, int K) {
        ta.d[ta.nd].W = W; ta.d[ta.nd].eoff = eoff; ta.d[ta.nd].WT = WT;
        ta.d[ta.nd].K = K; ta.d[ta.nd].tstart = tcum;
        tcum += (K / 32) * 8; ta.nd++;
    };
    addT(Ws1, 0, Ws1T, 1024); addT(Wf1, 0, Wf1T, 1024); addT(Wt1, 0, Wt1T, 2048);
    addT(Ws2, 0, Ws2T, 1024); addT(Wf2, 0, Wf2T, 1024); addT(Wt2, 0, Wt2T, 2048);
    addT(Ws3, 0, Ws3T, 1024); addT(Wf3, 0, Wf3T, 1024); addT(Wt3, 0, Wt3T, 1024);
    addT(G1W, 0,      G1WT,          256);
    addT(G2W, 0,      G2WT,          256); addT(G2W, 65536,  G2WT + 65536,  256);
    addT(G3W, 0,      G3WT,          256); addT(G3W, 65536,  G3WT + 65536,  256);
    addT(G3W, 131072, G3WT + 131072, 256);
    transpose_multi_k<<<tcum, 256, 0, stream>>>(ta, flag);

    auto addG = [](GArgs& A, int& cum, const void* Ain, int Kin, int isb, int ioff,
                   int rpb, int ext, const bf16_t* WT, const bf16_t* bias,
                   bf16_t* out, int osb, int ooff, int M) {
        GDesc& g = A.d[A.nd];
        g.A = Ain; g.WT = WT; g.bias = bias; g.out = out;
        g.Kin = Kin; g.in_stride_b = isb; g.in_off = ioff; g.rows_pb = rpb;
        g.a_is_ext = ext; g.out_stride_b = osb; g.out_off = ooff; g.mb_start = cum;
        cum += M / 128; A.nd++;
    };
    auto launchG = [&](GArgs& A, int cum) {
        A.total_mb = cum;
        int gp = (cum + 7) & ~7;               // pad groups to multiple of 8
        gemm_multi_k<<<gp * 2, 256, 0, stream>>>(A, flag);
    };

    // ---- ALL nine input projections (no inter-dependencies) in ONE launch ----
    GArgs pg; pg.nd = 0; int pc = 0;
    addG(pg, pc, scene_tv,   1024,  1, 0,  1, 1, Ws1T, cb[0], nodes1,   3,   0, NB);
    addG(pg, pc, face_tv,    1024,  1, 0,  1, 1, Wf1T, cb[1], nodes1,   3,   1, NB);
    addG(pg, pc, text_tv,    2048,  1, 0,  1, 1, Wt1T, cb[2], nodes1,   3,   2, NB);
    addG(pg, pc, scene_refs, 1024, 20, 0, 20, 1, Ws2T, cb[3], nodes2,  63,   3, NB*20);
    addG(pg, pc, face_refs,  1024, 20, 0, 20, 1, Wf2T, cb[4], nodes2,  63,  23, NB*20);
    addG(pg, pc, text_refs,  2048, 20, 0, 20, 1, Wt2T, cb[5], nodes2,  63,  43, NB*20);
    addG(pg, pc, scene_ra,   1024, 20, 0, 20, 1, Ws3T, cb[6], nodes3, 123,  63, NB*20);
    addG(pg, pc, face_ra,    1024, 20, 0, 20, 1, Wf3T, cb[7], nodes3, 123,  83, NB*20);
    addG(pg, pc, text_ra,    1024, 20, 0, 20, 1, Wt3T, cb[8], nodes3, 123, 103, NB*20);
    launchG(pg, pc);

    // -------- stage 1 --------
    GArgs g1; g1.nd = 0; int c1 = 0;
    addG(g1, c1, nodes1, 256, 3, 0, 3, 0, G1WT, nullptr, Wh1, 3, 0, NB*3);
    launchG(g1, c1);

    SArgs s1a; s1a.nd = 1;
    s1a.e[0].Wh = Wh1; s1a.e[0].as_ = a1s; s1a.e[0].ad_ = a1d;
    s1a.e[0].s = s1s; s1a.e[0].d = s1d; s1a.e[0].bstart = 0;
    scores_multi_k<<<NB*3/4, 256, 0, stream>>>(s1a);
    agg1_k<<<NB*3, 256, 0, stream>>>(Wh1, s1s, s1d, nodes2);

    // -------- stage 2 --------
    GArgs g2; g2.nd = 0; int c2 = 0;
    addG(g2, c2, nodes2, 256, 63, 0,  3, 0, G2WT,         nullptr, Wh1,  3, 0, NB*3);
    addG(g2, c2, nodes2, 256, 63, 0, 63, 0, G2WT + 65536, nullptr, Wh2, 63, 0, NB*63);
    launchG(g2, c2);

    SArgs s2a; s2a.nd = 2;
    s2a.e[0].Wh = Wh1; s2a.e[0].as_ = a2s;       s2a.e[0].ad_ = a2d;
    s2a.e[0].s = s1s;  s2a.e[0].d = s1d;         s2a.e[0].bstart = 0;
    s2a.e[1].Wh = Wh2; s2a.e[1].as_ = a2s + 256; s2a.e[1].ad_ = a2d + 256;
    s2a.e[1].s = s2s;  s2a.e[1].d = s2d;         s2a.e[1].bstart = NB*3/4;
    scores_multi_k<<<NB*3/4 + NB*63/4, 256, 0, stream>>>(s2a);
    agg2_k<<<NB*63, 256, 0, stream>>>(Wh1, Wh2, s1s, s1d, s2s, s2d, nodes3);

    // -------- stage 3 --------
    GArgs g3; g3.nd = 0; int c3 = 0;
    addG(g3, c3, nodes3, 256, 123,  0,  3, 0, G3WT,          nullptr, Wh1,  3, 0, NB*3);
    addG(g3, c3, nodes3, 256, 123,  0, 63, 0, G3WT + 65536,  nullptr, Wh2, 63, 0, NB*63);
    addG(g3, c3, nodes3, 256, 123,  0,  3, 0, G3WT + 131072, nullptr, Wh3, 63, 0, NB*3);
    addG(g3, c3, nodes3, 256, 123, 63, 60, 0, G3WT + 131072, nullptr, Wh3, 63, 3, NB*60);
    launchG(g3, c3);

    SArgs s3a; s3a.nd = 3;
    s3a.e[0].Wh = Wh1; s3a.e[0].as_ = a3s;       s3a.e[0].ad_ = a3d;
    s3a.e[0].s = s1s;  s3a.e[0].d = s1d;         s3a.e[0].bstart = 0;
    s3a.e[1].Wh = Wh2; s3a.e[1].as_ = a3s + 256; s3a.e[1].ad_ = a3d + 256;
    s3a.e[1].s = s2s;  s3a.e[1].d = s2d;         s3a.e[1].bstart = NB*3/4;
    s3a.e[2].Wh = Wh3; s3a.e[2].as_ = a3s + 512; s3a.e[2].ad_ = a3d + 512;
    s3a.e[2].s = s3s;  s3a.e[2].d = s3d;         s3a.e[2].bstart = NB*3/4 + NB*63/4;
    scores_multi_k<<<NB*3/4 + 2*(NB*63/4), 256, 0, stream>>>(s3a);
    agg3_k<<<NB*123, 256, 0, stream>>>(Wh1, Wh2, Wh3, s1s, s1d, s2s, s2d, s3s, s3d,
                                       d_out, flag);
}